// Round 1
// baseline (449.084 us; speedup 1.0000x reference)
//
#include <hip/hip_runtime.h>
#include <hip/hip_fp16.h>

#define B_SZ 2048
#define T_SZ 2048
#define F_SZ 8
#define LOG2E 1.44269504088896340736f

// ---------------------------------------------------------------------------
// Record format (workspace): for each (t, b), 24 bytes = 3 uint2, one per u:
//   rec[(t*B + b)*3 + u] = { pk(Az_u, Ar_u), pk(Xh_u, m) }   (fp16 pairs)
// where  Az_u = -log2e*(xw_z + bias_i_z + bias_r_z)
//        Ar_u = -log2e*(xw_r + bias_i_r + bias_r_r)
//        Xh_u = 2*log2e*(xw_h + bias_i_h)            (bias_r_h goes in scan)
//        m    = any(x[b,t,:] != 0) ? 1 : 0
// Pre-scaling makes sigmoid/tanh pure v_exp_f32 (2^x) in the scan:
//   z  = 1/(1 + 2^(Az + h.Rz'))          Rz' = -log2e*R[:,0:3]
//   r  = 1/(1 + 2^(Ar + h.Rr'))          Rr' = -log2e*R[:,3:6]
//   hc = 1 - 2/(1 + 2^(Xh + r*HH2))      HH2 = h.(2*log2e*R[:,6:9]) + 2*log2e*br_h
// ---------------------------------------------------------------------------

typedef __fp16 h2_t __attribute__((ext_vector_type(2)));

static __device__ __forceinline__ unsigned pk2(float a, float b) {
  h2_t v = __builtin_amdgcn_cvt_pkrtz(a, b);
  return __builtin_bit_cast(unsigned, v);
}

static __device__ __forceinline__ float2 up2(unsigned d) {
  __half2 h = __builtin_bit_cast(__half2, d);
  float2 f;
  f.x = __half2float(h.x);
  f.y = __half2float(h.y);
  return f;
}

// quad_perm DPP broadcast/butterfly (all lanes active at call sites)
template <int CTRL>
static __device__ __forceinline__ float qb(float v) {
  return __builtin_bit_cast(float,
      __builtin_amdgcn_mov_dpp(__builtin_bit_cast(int, v), CTRL, 0xF, 0xF, false));
}

// ---------------------------- Pass 1 ---------------------------------------
static __device__ __forceinline__ void do_step(const float xr[8],
                                               const float K[72],
                                               const float off[9],
                                               uint2* __restrict__ rp) {
  float A[9];
#pragma unroll
  for (int c = 0; c < 9; c++) {
    float acc = xr[0] * K[0 * 9 + c];
#pragma unroll
    for (int f = 1; f < 8; f++) acc = fmaf(xr[f], K[f * 9 + c], acc);
    float sc = (c < 6) ? -LOG2E : 2.0f * LOG2E;
    A[c] = fmaf(sc, acc, off[c]);
  }
  bool any = false;
#pragma unroll
  for (int f = 0; f < 8; f++) any = any || (xr[f] != 0.0f);
  float mf = any ? 1.0f : 0.0f;
  uint2 r0, r1, r2;
  r0.x = pk2(A[0], A[3]); r0.y = pk2(A[6], mf);
  r1.x = pk2(A[1], A[4]); r1.y = pk2(A[7], mf);
  r2.x = pk2(A[2], A[5]); r2.y = pk2(A[8], mf);
  rp[0] = r0; rp[1] = r1; rp[2] = r2;
}

__global__ __launch_bounds__(256) void gru_pass1(
    const float* __restrict__ x, const float* __restrict__ kern,
    const float* __restrict__ bi, const float* __restrict__ br,
    uint2* __restrict__ rec) {
  unsigned g = blockIdx.x * 256u + threadIdx.x;
  unsigned b = g & (B_SZ - 1);          // b fastest -> coalesced record writes
  unsigned t = (g >> 11) << 1;          // each thread does timesteps t, t+1

  float K[72];
#pragma unroll
  for (int i = 0; i < 72; i++) K[i] = kern[i];   // uniform -> SGPRs
  float off[9];
#pragma unroll
  for (int c = 0; c < 9; c++)
    off[c] = (c < 6) ? (-LOG2E * (bi[c] + br[c])) : (2.0f * LOG2E * bi[c]);

  // 64B-aligned full-cache-line read of x[b, t:t+2, :]
  const float4* xp = (const float4*)(x + ((size_t)b * T_SZ + t) * F_SZ);
  float4 a0 = xp[0], a1 = xp[1], a2 = xp[2], a3 = xp[3];
  float x0[8] = {a0.x, a0.y, a0.z, a0.w, a1.x, a1.y, a1.z, a1.w};
  float x1[8] = {a2.x, a2.y, a2.z, a2.w, a3.x, a3.y, a3.z, a3.w};

  uint2* rp = rec + ((size_t)t * B_SZ + b) * 3;
  do_step(x0, K, off, rp);
  do_step(x1, K, off, rp + (size_t)B_SZ * 3);
}

// ---------------------------- Pass 2 (scan) --------------------------------
// 4 lanes per batch row: lane u in {0,1,2} owns hidden unit u; lane 3 spare.
__global__ __launch_bounds__(256) void gru_scan(
    const uint2* __restrict__ rec, const float* __restrict__ rk,
    const float* __restrict__ br, const float* __restrict__ dw,
    const float* __restrict__ db, float* __restrict__ out) {
  unsigned tid = blockIdx.x * 256u + threadIdx.x;
  unsigned b = tid >> 2;
  unsigned u = tid & 3u;

  float Rz0 = 0, Rz1 = 0, Rz2 = 0, Rr0 = 0, Rr1 = 0, Rr2 = 0;
  float Rh0 = 0, Rh1 = 0, Rh2 = 0, Ch = 0, wl = 0;
  if (u < 3) {
    Rz0 = -LOG2E * rk[0 * 9 + u];
    Rz1 = -LOG2E * rk[1 * 9 + u];
    Rz2 = -LOG2E * rk[2 * 9 + u];
    Rr0 = -LOG2E * rk[0 * 9 + 3 + u];
    Rr1 = -LOG2E * rk[1 * 9 + 3 + u];
    Rr2 = -LOG2E * rk[2 * 9 + 3 + u];
    Rh0 = 2.0f * LOG2E * rk[0 * 9 + 6 + u];
    Rh1 = 2.0f * LOG2E * rk[1 * 9 + 6 + u];
    Rh2 = 2.0f * LOG2E * rk[2 * 9 + 6 + u];
    Ch = 2.0f * LOG2E * br[6 + u];
    wl = dw[u];                          // lane3: wl=0 -> contributes 0 to dot
  }
  float dbv = db[0];

  const char* base = (const char*)rec;
  unsigned lidx = b * 3u + u;
  if (lidx > 3u * B_SZ - 1u) lidx = 3u * B_SZ - 1u;  // clamp lane3 of b=2047
  unsigned lane_off = lidx * 8u;

  constexpr int D = 16;  // prefetch depth: D * ~90cyc > 900cyc HBM latency
  uint2 buf[D];
#pragma unroll
  for (int i = 0; i < D; i++)
    buf[i] = *(const uint2*)(base + (unsigned)i * 49152u + lane_off);

  float h = 0.0f;
  float o0 = 0, o1 = 0, o2 = 0, o3 = 0;

  for (int tt = 0; tt < T_SZ; tt += D) {
#pragma unroll
    for (int j = 0; j < D; j++) {
      int t = tt + j;
      uint2 c = buf[j];
      unsigned tn = (unsigned)(t + D);
      if (tn > T_SZ - 1u) tn = T_SZ - 1u;  // clamped redundant tail prefetch
      buf[j] = *(const uint2*)(base + tn * 49152u + lane_off);

      float2 pa = up2(c.x);  // (Az, Ar)
      float2 pb = up2(c.y);  // (Xh, m)

      float h0 = qb<0x00>(h);  // broadcast lane0's h within quad
      float h1 = qb<0x55>(h);
      float h2 = qb<0xAA>(h);

      float tz = fmaf(h0, Rz0, pa.x); tz = fmaf(h1, Rz1, tz); tz = fmaf(h2, Rz2, tz);
      float tr = fmaf(h0, Rr0, pa.y); tr = fmaf(h1, Rr1, tr); tr = fmaf(h2, Rr2, tr);
      float hh = fmaf(h0, Rh0, Ch);   hh = fmaf(h1, Rh1, hh); hh = fmaf(h2, Rh2, hh);

      float z = __builtin_amdgcn_rcpf(1.0f + __builtin_amdgcn_exp2f(tz));
      float r = __builtin_amdgcn_rcpf(1.0f + __builtin_amdgcn_exp2f(tr));
      float arg = fmaf(r, hh, pb.x);
      float qd = __builtin_amdgcn_rcpf(1.0f + __builtin_amdgcn_exp2f(arg));
      float hc = fmaf(-2.0f, qd, 1.0f);  // tanh

      float t1 = hc - h;
      float s = fmaf(-z, t1, t1);   // (1-z)*(hc-h) = h_full - h
      float hf = h + s;             // h_new_full
      h = fmaf(pb.y, s, h);         // masked carry: m ? h_full : h

      float p = hf * wl;            // dense dot via quad butterfly
      p += qb<0xB1>(p);
      p += qb<0x4E>(p);
      float ov = fmaf(pb.y, p, dbv);  // m ? dot+db : db

      if ((j & 3) == 0) o0 = ov;
      else if ((j & 3) == 1) o1 = ov;
      else if ((j & 3) == 2) o2 = ov;
      else {
        o3 = ov;
        if (u == 0) {
          float4 v;
          v.x = o0; v.y = o1; v.z = o2; v.w = o3;
          *(float4*)(out + (size_t)b * T_SZ + (t - 3)) = v;
        }
      }
    }
  }
}

// ---------------------------------------------------------------------------
extern "C" void kernel_launch(void* const* d_in, const int* in_sizes, int n_in,
                              void* d_out, int out_size, void* d_ws,
                              size_t ws_size, hipStream_t stream) {
  const float* x  = (const float*)d_in[0];
  const float* k  = (const float*)d_in[1];
  const float* rk = (const float*)d_in[2];
  const float* bi = (const float*)d_in[3];
  const float* br = (const float*)d_in[4];
  const float* dw = (const float*)d_in[5];
  const float* db = (const float*)d_in[6];
  float* out = (float*)d_out;
  uint2* rec = (uint2*)d_ws;  // needs T*B*24 = 100,663,296 bytes

  // Pass 1: B*T/2 threads, each does 2 timesteps (one 64B line of x)
  hipLaunchKernelGGL(gru_pass1, dim3((B_SZ * T_SZ / 2) / 256), dim3(256), 0,
                     stream, x, k, bi, br, rec);
  // Pass 2: 4 lanes per batch row
  hipLaunchKernelGGL(gru_scan, dim3((B_SZ * 4) / 256), dim3(256), 0, stream,
                     rec, rk, br, dw, db, out);
}

// Round 2
// 374.932 us; speedup vs baseline: 1.1978x; 1.1978x over previous
//
#include <hip/hip_runtime.h>
#include <hip/hip_fp16.h>

#define B_SZ 2048
#define T_SZ 2048
#define F_SZ 8
#define LOG2E 1.44269504088896340736f

// ---------------------------------------------------------------------------
// Record layout (workspace), B-MAJOR: for each (b, t), 24 bytes = 3 uint2:
//   rec[((size_t)b*T + t)*3 + u] = { pk(Az_u, Ar_u), pk(Xh_u, m) }  (fp16)
// where  Az_u = -log2e*(xw_z + bias_i_z + bias_r_z)
//        Ar_u = -log2e*(xw_r + bias_i_r + bias_r_r)
//        Xh_u = 2*log2e*(xw_h + bias_i_h)          (bias_r_h folded in scan)
//        m    = any(x[b,t,:] != 0) ? 1 : 0
// Pre-scaling makes sigmoid/tanh pure v_exp_f32 (2^x) in the scan.
// ---------------------------------------------------------------------------

typedef __fp16 h2_t __attribute__((ext_vector_type(2)));

static __device__ __forceinline__ unsigned pk2(float a, float b) {
  h2_t v = __builtin_amdgcn_cvt_pkrtz(a, b);
  return __builtin_bit_cast(unsigned, v);
}

static __device__ __forceinline__ float2 up2(unsigned d) {
  __half2 h = __builtin_bit_cast(__half2, d);
  float2 f;
  f.x = __half2float(h.x);
  f.y = __half2float(h.y);
  return f;
}

static __device__ __forceinline__ float rfl(float v) {
  return __builtin_bit_cast(float,
      __builtin_amdgcn_readfirstlane(__builtin_bit_cast(int, v)));
}

// quad_perm DPP broadcast/butterfly (all lanes active at call sites)
template <int CTRL>
static __device__ __forceinline__ float bcast(float v) {
  return __builtin_bit_cast(float,
      __builtin_amdgcn_mov_dpp(__builtin_bit_cast(int, v), CTRL, 0xF, 0xF, false));
}

// ---------------------------- Pass 1 ---------------------------------------
static __device__ __forceinline__ void do_step(const float xr[8],
                                               const float K[72],
                                               const float off[9],
                                               unsigned o[6]) {
  float A[9];
#pragma unroll
  for (int c = 0; c < 9; c++) {
    float acc = xr[0] * K[0 * 9 + c];
#pragma unroll
    for (int f = 1; f < 8; f++) acc = fmaf(xr[f], K[f * 9 + c], acc);
    float sc = (c < 6) ? -LOG2E : 2.0f * LOG2E;
    A[c] = fmaf(sc, acc, off[c]);
  }
  bool any = false;
#pragma unroll
  for (int f = 0; f < 8; f++) any = any || (xr[f] != 0.0f);
  float mf = any ? 1.0f : 0.0f;
  o[0] = pk2(A[0], A[3]); o[1] = pk2(A[6], mf);
  o[2] = pk2(A[1], A[4]); o[3] = pk2(A[7], mf);
  o[4] = pk2(A[2], A[5]); o[5] = pk2(A[8], mf);
}

__global__ __launch_bounds__(256) void gru_pass1(
    const float* __restrict__ x, const float* __restrict__ kern,
    const float* __restrict__ bi, const float* __restrict__ br,
    uint4* __restrict__ rec) {
  unsigned g = blockIdx.x * 256u + threadIdx.x;
  unsigned b = g >> 10;                 // lanes consecutive in t -> coalesced
  unsigned t = (g & 1023u) << 1;        // each thread does timesteps t, t+1

  float K[72];
#pragma unroll
  for (int i = 0; i < 72; i++) K[i] = rfl(kern[i]);  // uniform -> SGPRs
  float off[9];
#pragma unroll
  for (int c = 0; c < 9; c++)
    off[c] = rfl((c < 6) ? (-LOG2E * (bi[c] + br[c])) : (2.0f * LOG2E * bi[c]));

  // 64B full-cache-line read of x[b, t:t+2, :], coalesced across the wave
  const float4* xp = (const float4*)(x + ((size_t)b * T_SZ + t) * F_SZ);
  float4 a0 = xp[0], a1 = xp[1], a2 = xp[2], a3 = xp[3];
  float x0[8] = {a0.x, a0.y, a0.z, a0.w, a1.x, a1.y, a1.z, a1.w};
  float x1[8] = {a2.x, a2.y, a2.z, a2.w, a3.x, a3.y, a3.z, a3.w};

  unsigned r0[6], r1[6];
  do_step(x0, K, off, r0);
  do_step(x1, K, off, r1);

  // 48 contiguous bytes per lane -> 3 x dwordx4, fully coalesced
  uint4* wp = rec + ((size_t)b * T_SZ + t) * 24u / 16u;
  uint4 w0, w1, w2;
  w0.x = r0[0]; w0.y = r0[1]; w0.z = r0[2]; w0.w = r0[3];
  w1.x = r0[4]; w1.y = r0[5]; w1.z = r1[0]; w1.w = r1[1];
  w2.x = r1[2]; w2.y = r1[3]; w2.z = r1[4]; w2.w = r1[5];
  wp[0] = w0; wp[1] = w1; wp[2] = w2;
}

// ---------------------------- Pass 2 (scan) --------------------------------
// 4 lanes per batch row: lane u in {0,1,2} owns hidden unit u; lane 3 spare
// (reads a duplicate of u=2, wl=0 so it contributes nothing).
// Double-buffered 16-step pipeline in NAMED registers (no arrays -> no
// scratch demotion; prev round's VGPR_Count=36 proved buf[] was demoted).

#define DECL16(P) \
  uint2 P##0, P##1, P##2, P##3, P##4, P##5, P##6, P##7, P##8, P##9, P##10, \
      P##11, P##12, P##13, P##14, P##15

#define LOAD16(P, q) \
  do { \
    const char* _q = (q); \
    P##0 = *(const uint2*)(_q + 0 * 24); \
    P##1 = *(const uint2*)(_q + 1 * 24); \
    P##2 = *(const uint2*)(_q + 2 * 24); \
    P##3 = *(const uint2*)(_q + 3 * 24); \
    P##4 = *(const uint2*)(_q + 4 * 24); \
    P##5 = *(const uint2*)(_q + 5 * 24); \
    P##6 = *(const uint2*)(_q + 6 * 24); \
    P##7 = *(const uint2*)(_q + 7 * 24); \
    P##8 = *(const uint2*)(_q + 8 * 24); \
    P##9 = *(const uint2*)(_q + 9 * 24); \
    P##10 = *(const uint2*)(_q + 10 * 24); \
    P##11 = *(const uint2*)(_q + 11 * 24); \
    P##12 = *(const uint2*)(_q + 12 * 24); \
    P##13 = *(const uint2*)(_q + 13 * 24); \
    P##14 = *(const uint2*)(_q + 14 * 24); \
    P##15 = *(const uint2*)(_q + 15 * 24); \
  } while (0)

#define STEP(J, C, tb) \
  do { \
    float2 pa = up2((C).x); \
    float2 pb = up2((C).y); \
    float h0 = bcast<0x00>(h); \
    float h1 = bcast<0x55>(h); \
    float h2 = bcast<0xAA>(h); \
    float tz = fmaf(h0, Rz0, pa.x); tz = fmaf(h1, Rz1, tz); tz = fmaf(h2, Rz2, tz); \
    float tr = fmaf(h0, Rr0, pa.y); tr = fmaf(h1, Rr1, tr); tr = fmaf(h2, Rr2, tr); \
    float hh = fmaf(h0, Rh0, Ch);   hh = fmaf(h1, Rh1, hh); hh = fmaf(h2, Rh2, hh); \
    float z = __builtin_amdgcn_rcpf(1.0f + __builtin_amdgcn_exp2f(tz)); \
    float r = __builtin_amdgcn_rcpf(1.0f + __builtin_amdgcn_exp2f(tr)); \
    float arg = fmaf(r, hh, pb.x); \
    float qd = __builtin_amdgcn_rcpf(1.0f + __builtin_amdgcn_exp2f(arg)); \
    float hc = fmaf(-2.0f, qd, 1.0f); \
    float t1 = hc - h; \
    float s = fmaf(-z, t1, t1); \
    float hf = h + s; \
    h = fmaf(pb.y, s, h); \
    float pp = hf * wl; \
    pp += bcast<0xB1>(pp); \
    pp += bcast<0x4E>(pp); \
    float ov = fmaf(pb.y, pp, dbv); \
    if (((J) & 3) == 0) o0 = ov; \
    else if (((J) & 3) == 1) o1 = ov; \
    else if (((J) & 3) == 2) o2 = ov; \
    else if (u == 0) { \
      float4 v; v.x = o0; v.y = o1; v.z = o2; v.w = ov; \
      *(float4*)(out + (size_t)b * T_SZ + (tb) + (J) - 3) = v; \
    } \
  } while (0)

#define COMPUTE16(P, tb) \
  do { \
    STEP(0, P##0, tb);  STEP(1, P##1, tb);  STEP(2, P##2, tb); \
    STEP(3, P##3, tb);  STEP(4, P##4, tb);  STEP(5, P##5, tb); \
    STEP(6, P##6, tb);  STEP(7, P##7, tb);  STEP(8, P##8, tb); \
    STEP(9, P##9, tb);  STEP(10, P##10, tb); STEP(11, P##11, tb); \
    STEP(12, P##12, tb); STEP(13, P##13, tb); STEP(14, P##14, tb); \
    STEP(15, P##15, tb); \
  } while (0)

__global__ __launch_bounds__(64) void gru_scan(
    const char* __restrict__ rec, const float* __restrict__ rk,
    const float* __restrict__ br, const float* __restrict__ dw,
    const float* __restrict__ db, float* __restrict__ out) {
  unsigned tid = blockIdx.x * 64u + threadIdx.x;
  unsigned b = tid >> 2;
  unsigned u = tid & 3u;

  float Rz0 = 0, Rz1 = 0, Rz2 = 0, Rr0 = 0, Rr1 = 0, Rr2 = 0;
  float Rh0 = 0, Rh1 = 0, Rh2 = 0, Ch = 0, wl = 0;
  if (u < 3) {
    Rz0 = -LOG2E * rk[0 * 9 + u];
    Rz1 = -LOG2E * rk[1 * 9 + u];
    Rz2 = -LOG2E * rk[2 * 9 + u];
    Rr0 = -LOG2E * rk[0 * 9 + 3 + u];
    Rr1 = -LOG2E * rk[1 * 9 + 3 + u];
    Rr2 = -LOG2E * rk[2 * 9 + 3 + u];
    Rh0 = 2.0f * LOG2E * rk[0 * 9 + 6 + u];
    Rh1 = 2.0f * LOG2E * rk[1 * 9 + 6 + u];
    Rh2 = 2.0f * LOG2E * rk[2 * 9 + 6 + u];
    Ch = 2.0f * LOG2E * br[6 + u];
    wl = dw[u];  // lane3: wl=0 -> contributes 0 to the quad dot
  }
  float dbv = db[0];

  unsigned uoff = (u < 3u) ? u * 8u : 16u;  // lane3 duplicates u=2 (in-bounds)
  const char* p = rec + (size_t)b * T_SZ * 24u + uoff;

  DECL16(A);
  DECL16(B);
  LOAD16(A, p);  // t = 0..15

  float h = 0.0f;
  float o0 = 0, o1 = 0, o2 = 0;

  for (unsigned t0 = 0; t0 < T_SZ; t0 += 32) {
    LOAD16(B, p + (size_t)(t0 + 16) * 24u);            // t0+16 <= 2032: in-bounds
    COMPUTE16(A, t0);
    const char* pA = (t0 + 32 < T_SZ) ? (p + (size_t)(t0 + 32) * 24u) : p;
    LOAD16(A, pA);                                     // last iter: dummy reload
    COMPUTE16(B, t0 + 16);
  }
}

// ---------------------------------------------------------------------------
extern "C" void kernel_launch(void* const* d_in, const int* in_sizes, int n_in,
                              void* d_out, int out_size, void* d_ws,
                              size_t ws_size, hipStream_t stream) {
  const float* x  = (const float*)d_in[0];
  const float* k  = (const float*)d_in[1];
  const float* rk = (const float*)d_in[2];
  const float* bi = (const float*)d_in[3];
  const float* br = (const float*)d_in[4];
  const float* dw = (const float*)d_in[5];
  const float* db = (const float*)d_in[6];
  float* out = (float*)d_out;

  // Pass 1: B*T/2 threads, each does 2 timesteps (one 64B line of x)
  hipLaunchKernelGGL(gru_pass1, dim3((B_SZ * T_SZ / 2) / 256), dim3(256), 0,
                     stream, x, k, bi, br, (uint4*)d_ws);
  // Pass 2: 4 lanes per batch row, 64-thread blocks spread across CUs
  hipLaunchKernelGGL(gru_scan, dim3((B_SZ * 4) / 64), dim3(64), 0, stream,
                     (const char*)d_ws, rk, br, dw, db, out);
}